// Round 3
// baseline (318.901 us; speedup 1.0000x reference)
//
#include <hip/hip_runtime.h>
#include <hip/hip_bf16.h>
#include <hip/hip_fp16.h>

// Problem constants
#define N0 200000
#define N1 50000
#define N2 10000
#define E1C 800000
#define E2C 160000
// IN_F=128, HID=128, RANK=64, OUT_C=64
#define NB1 784      // ceil(50000/64)=782, padded to mult of 8
#define NB2 160      // ceil(10000/64)=157, padded to mult of 8
#define NBT (NB1 + NB2)
#define CH1 64
#define CH2 16
#define NTP 12500    // N0/16 projection tiles
#define NT1 3125     // N1/16
#define NT2 625      // N2/16
#define SCAP 2048    // LDS sort capacity (expected 1562, +13 sigma)

struct H8 { __half2 a, b, c, d; };        // 16 B

typedef _Float16 f16x8 __attribute__((ext_vector_type(8)));
typedef float f32x4 __attribute__((ext_vector_type(4)));
#define MFMA16(a, b, c) __builtin_amdgcn_mfma_f32_16x16x32_f16(a, b, c, 0, 0, 0)

// Transposed fp16 weight block offsets (halves):
// Wsrc1t[64][128]@0, Wdst1t[64][128]@8192, Wout1t[128][64]@16384,
// Wsrc2t[64][128]@24576, Wdst2t[64][128]@32768, Wout2t[64][64]@40960
#define WT_TOTAL 45056

// ---------------------------------------------------------------------------
// K1: blocks 0..79 = per-chunk histograms into PRIVATE slices (no zero, no
// global atomics); blocks 80..255 = fp16 transposed weight build.
__global__ __launch_bounds__(256) void prep_count(const int* __restrict__ dst1,
                                                  const int* __restrict__ dst2,
                                                  int* __restrict__ hist_part,
                                                  const float* __restrict__ Wsrc1,
                                                  const float* __restrict__ Wdst1,
                                                  const float* __restrict__ Wout1,
                                                  const float* __restrict__ Wsrc2,
                                                  const float* __restrict__ Wdst2,
                                                  const float* __restrict__ Wout2,
                                                  __half* __restrict__ wt) {
    int b = blockIdx.x;
    if (b < CH1 + CH2) {
        __shared__ int hl[NB1];
        const int* dst; int nb, e0, n4, hoff;
        if (b < CH1) {
            dst = dst1; nb = NB1; int per = E1C / CH1 / 4; e0 = b * per; n4 = per;
            hoff = b * NB1;
        } else {
            dst = dst2; nb = NB2; int per = E2C / CH2 / 4; int c = b - CH1;
            e0 = c * per; n4 = per;
            hoff = CH1 * NB1 + c * NB2;
        }
        for (int i = threadIdx.x; i < nb; i += 256) hl[i] = 0;
        __syncthreads();
        const int4* d4 = reinterpret_cast<const int4*>(dst);
        for (int i = e0 + threadIdx.x; i < e0 + n4; i += 256) {
            int4 v = d4[i];
            atomicAdd(&hl[v.x >> 6], 1);
            atomicAdd(&hl[v.y >> 6], 1);
            atomicAdd(&hl[v.z >> 6], 1);
            atomicAdd(&hl[v.w >> 6], 1);
        }
        __syncthreads();
        for (int i = threadIdx.x; i < nb; i += 256) hist_part[hoff + i] = hl[i];
    } else {
        int e = (b - (CH1 + CH2)) * 256 + threadIdx.x;
        if (e < WT_TOTAL) {
            float v;
            if (e < 8192)       { int e2 = e;         int n = e2 >> 7, k = e2 & 127; v = Wsrc1[k * 64 + n]; }
            else if (e < 16384) { int e2 = e - 8192;  int n = e2 >> 7, k = e2 & 127; v = Wdst1[k * 64 + n]; }
            else if (e < 24576) { int e2 = e - 16384; int n = e2 >> 6, k = e2 & 63;  v = Wout1[k * 128 + n]; }
            else if (e < 32768) { int e2 = e - 24576; int n = e2 >> 7, k = e2 & 127; v = Wsrc2[k * 64 + n]; }
            else if (e < 40960) { int e2 = e - 32768; int n = e2 >> 7, k = e2 & 127; v = Wdst2[k * 64 + n]; }
            else                { int e2 = e - 40960; int n = e2 >> 6, k = e2 & 63;  v = Wout2[k * 64 + n]; }
            wt[e] = __float2half(v);
        }
    }
}

// ---------------------------------------------------------------------------
// K2: sum private slices -> hist, exclusive scan -> base, cursor.
__global__ __launch_bounds__(1024) void scan_sum(const int* __restrict__ hp,
                                                 int* __restrict__ hist,
                                                 int* __restrict__ base,
                                                 int* __restrict__ cursor) {
    int t = threadIdx.x, lane = t & 63, wid = t >> 6;
    int v = 0;
    if (t < NB1) {
        #pragma unroll 8
        for (int c = 0; c < CH1; ++c) v += hp[c * NB1 + t];
    } else if (t < NBT) {
        const int* hp2 = hp + CH1 * NB1;
        int j = t - NB1;
        #pragma unroll
        for (int c = 0; c < CH2; ++c) v += hp2[c * NB2 + j];
    }
    if (t < NBT) hist[t] = v;
    int s = v;
    #pragma unroll
    for (int o = 1; o < 64; o <<= 1) { int u = __shfl_up(s, o, 64); if (lane >= o) s += u; }
    __shared__ int ws[16];
    if (lane == 63) ws[wid] = s;
    __syncthreads();
    if (wid == 0 && lane < 16) {
        int w = ws[lane];
        #pragma unroll
        for (int o = 1; o < 16; o <<= 1) { int u = __shfl_up(w, o, 64); if (lane >= o) w += u; }
        ws[lane] = w;
    }
    __syncthreads();
    int excl = ((wid == 0) ? 0 : ws[wid - 1]) + (s - v);
    if (t < NBT) { base[t] = excl; cursor[t] = excl; }
}

// ---------------------------------------------------------------------------
// K3: LDS counting-sort scatter. Per (partition, chunk) block: count, LDS
// scan, place sorted into LDS (bucket id in bits 24..30), one global
// reservation per bucket, COALESCED burst emit.
__global__ __launch_bounds__(256) void sort_scatter(const int* __restrict__ dst1,
                                                    const int* __restrict__ src1,
                                                    const int* __restrict__ dst2,
                                                    const int* __restrict__ src2,
                                                    int* __restrict__ cursor,
                                                    int* __restrict__ edgebuf) {
    __shared__ int cnt_l[98], lbase[98], rsv[98], lcur[98];
    __shared__ int slot[SCAP];
    __shared__ int stot[2];
    int b = blockIdx.x;
    const int* dst; const int* srcp; int goff, bpp, lo, e0, e1;
    if (b < 8 * CH1) {
        dst = dst1; srcp = src1; goff = 0; bpp = NB1 / 8;
        int part = b & 7, chunk = b >> 3;
        lo = part * bpp;
        int per = E1C / CH1 / 4;
        e0 = chunk * per; e1 = e0 + per;
    } else {
        int k = b - 8 * CH1;
        dst = dst2; srcp = src2; goff = NB1; bpp = NB2 / 8;
        int part = k & 7, chunk = k >> 3;
        lo = part * bpp;
        int per = E2C / CH2 / 4;
        e0 = chunk * per; e1 = e0 + per;
    }
    int t = threadIdx.x;
    for (int i = t; i < bpp; i += 256) { cnt_l[i] = 0; lcur[i] = 0; }
    __syncthreads();
    const int4* d4 = reinterpret_cast<const int4*>(dst);
    const int4* s4 = reinterpret_cast<const int4*>(srcp);
    // pass 1: count
    for (int i = e0 + t; i < e1; i += 256) {
        int4 v = d4[i];
        int b0 = (v.x >> 6) - lo; if ((unsigned)b0 < (unsigned)bpp) atomicAdd(&cnt_l[b0], 1);
        int b1 = (v.y >> 6) - lo; if ((unsigned)b1 < (unsigned)bpp) atomicAdd(&cnt_l[b1], 1);
        int b2 = (v.z >> 6) - lo; if ((unsigned)b2 < (unsigned)bpp) atomicAdd(&cnt_l[b2], 1);
        int b3 = (v.w >> 6) - lo; if ((unsigned)b3 < (unsigned)bpp) atomicAdd(&cnt_l[b3], 1);
    }
    __syncthreads();
    // two-wave exclusive scan of cnt_l[0..bpp)
    if (t < 128) {
        int j = t;                 // wave0: bins 0..63, wave1: bins 64..127
        int lane6 = t & 63;
        int v = (j < bpp) ? cnt_l[j] : 0;
        int s = v;
        #pragma unroll
        for (int o = 1; o < 64; o <<= 1) { int u = __shfl_up(s, o, 64); if (lane6 >= o) s += u; }
        if (lane6 == 63) stot[t >> 6] = s;
        if (j < bpp) lbase[j] = s - v;
    }
    __syncthreads();
    if (t >= 64 && t < 128) {
        int j = t;
        if (j < bpp) lbase[j] += stot[0];
    }
    __syncthreads();
    int T = stot[0] + stot[1];
    if (T <= SCAP) {
        // place into LDS sorted positions
        for (int i = e0 + t; i < e1; i += 256) {
            int4 dv = d4[i];
            int4 sv = s4[i];
            int b0 = (dv.x >> 6) - lo;
            if ((unsigned)b0 < (unsigned)bpp) { int p = atomicAdd(&lcur[b0], 1); slot[lbase[b0] + p] = (b0 << 24) | (sv.x << 6) | (dv.x & 63); }
            int b1 = (dv.y >> 6) - lo;
            if ((unsigned)b1 < (unsigned)bpp) { int p = atomicAdd(&lcur[b1], 1); slot[lbase[b1] + p] = (b1 << 24) | (sv.y << 6) | (dv.y & 63); }
            int b2 = (dv.z >> 6) - lo;
            if ((unsigned)b2 < (unsigned)bpp) { int p = atomicAdd(&lcur[b2], 1); slot[lbase[b2] + p] = (b2 << 24) | (sv.z << 6) | (dv.z & 63); }
            int b3 = (dv.w >> 6) - lo;
            if ((unsigned)b3 < (unsigned)bpp) { int p = atomicAdd(&lcur[b3], 1); slot[lbase[b3] + p] = (b3 << 24) | (sv.w << 6) | (dv.w & 63); }
        }
        if (t < bpp) rsv[t] = cnt_l[t] ? atomicAdd(&cursor[goff + lo + t], cnt_l[t]) : 0;
        __syncthreads();
        // coalesced emit: consecutive t in a bucket -> consecutive global addrs
        for (int u = t; u < T; u += 256) {
            int w = slot[u];
            int bx = (unsigned)w >> 24;
            edgebuf[rsv[bx] + (u - lbase[bx])] = w & 0x00FFFFFF;
        }
    } else {
        // fallback (statistically unreachable): scattered direct writes
        if (t < bpp) rsv[t] = cnt_l[t] ? atomicAdd(&cursor[goff + lo + t], cnt_l[t]) : 0;
        __syncthreads();
        for (int i = e0 + t; i < e1; i += 256) {
            int4 dv = d4[i];
            int4 sv = s4[i];
            int b0 = (dv.x >> 6) - lo;
            if ((unsigned)b0 < (unsigned)bpp) { int p = atomicAdd(&lcur[b0], 1); edgebuf[rsv[b0] + p] = (sv.x << 6) | (dv.x & 63); }
            int b1 = (dv.y >> 6) - lo;
            if ((unsigned)b1 < (unsigned)bpp) { int p = atomicAdd(&lcur[b1], 1); edgebuf[rsv[b1] + p] = (sv.y << 6) | (dv.y & 63); }
            int b2 = (dv.z >> 6) - lo;
            if ((unsigned)b2 < (unsigned)bpp) { int p = atomicAdd(&lcur[b2], 1); edgebuf[rsv[b2] + p] = (sv.z << 6) | (dv.z & 63); }
            int b3 = (dv.w >> 6) - lo;
            if ((unsigned)b3 < (unsigned)bpp) { int p = atomicAdd(&lcur[b3], 1); edgebuf[rsv[b3] + p] = (sv.w << 6) | (dv.w & 63); }
        }
    }
}

// ---------------------------------------------------------------------------
// K4: proj1 (unchanged): h_src1 = fp16(x @ Wsrc1) all rows; h_dst1 for rows<N1.
__global__ __launch_bounds__(256) void proj1(const float* __restrict__ x,
                                             const __half* __restrict__ wth,
                                             __half* __restrict__ hsrc,
                                             __half* __restrict__ hdst) {
    int wave = threadIdx.x >> 6, lane = threadIdx.x & 63;
    int tile = blockIdx.x * 4 + wave;
    if (tile >= NTP) return;
    int r0 = tile * 16;
    int m = lane & 15, q = lane >> 4;
    const float* A = x + (size_t)(r0 + m) * 128 + q * 8;
    const _Float16* wt = (const _Float16*)wth;
    const _Float16* Wsrc = wt;               // [64][128]
    const _Float16* Wdst = wt + 8192;        // [64][128]

    f16x8 a[4];
    #pragma unroll
    for (int kc = 0; kc < 4; ++kc) {
        float4 v0 = *(const float4*)(A + kc * 32);
        float4 v1 = *(const float4*)(A + kc * 32 + 4);
        f16x8 tv;
        tv[0] = (_Float16)v0.x; tv[1] = (_Float16)v0.y; tv[2] = (_Float16)v0.z; tv[3] = (_Float16)v0.w;
        tv[4] = (_Float16)v1.x; tv[5] = (_Float16)v1.y; tv[6] = (_Float16)v1.z; tv[7] = (_Float16)v1.w;
        a[kc] = tv;
    }
    f32x4 accS[4];
    #pragma unroll
    for (int nt = 0; nt < 4; ++nt) accS[nt] = (f32x4)(0.0f);
    #pragma unroll
    for (int kc = 0; kc < 4; ++kc)
        #pragma unroll
        for (int nt = 0; nt < 4; ++nt) {
            f16x8 bb = *(const f16x8*)(Wsrc + (nt * 16 + m) * 128 + kc * 32 + q * 8);
            accS[nt] = MFMA16(a[kc], bb, accS[nt]);
        }
    #pragma unroll
    for (int nt = 0; nt < 4; ++nt)
        #pragma unroll
        for (int i = 0; i < 4; ++i)
            hsrc[(size_t)(r0 + q * 4 + i) * 64 + nt * 16 + m] = __float2half(accS[nt][i]);

    if (tile < NT1) {
        f32x4 accD[4];
        #pragma unroll
        for (int nt = 0; nt < 4; ++nt) accD[nt] = (f32x4)(0.0f);
        #pragma unroll
        for (int kc = 0; kc < 4; ++kc)
            #pragma unroll
            for (int nt = 0; nt < 4; ++nt) {
                f16x8 bb = *(const f16x8*)(Wdst + (nt * 16 + m) * 128 + kc * 32 + q * 8);
                accD[nt] = MFMA16(a[kc], bb, accD[nt]);
            }
        #pragma unroll
        for (int nt = 0; nt < 4; ++nt)
            #pragma unroll
            for (int i = 0; i < 4; ++i)
                hdst[(size_t)(r0 + q * 4 + i) * 64 + nt * 16 + m] = __float2half(accD[nt][i]);
    }
}

// ---------------------------------------------------------------------------
// K5: fused seg-mean(rank64) + layer1. agg lives in LDS only.
// Phase A: ELL build + gather-mean -> agg_lds[64][72].
// Phase B: per wave 16-row tile: z = agg*hdst1 -> @Wout1 +b1, relu ->
//          @Wsrc2 (all rows) and @Wdst2 (rows<N2) -> global fp16.
__global__ __launch_bounds__(256) void seg1l1(const __half* __restrict__ X,
                                              const __half* __restrict__ hdst1,
                                              const int* __restrict__ edgebuf,
                                              const int* __restrict__ base,
                                              const int* __restrict__ hist,
                                              const __half* __restrict__ wth,
                                              const float* __restrict__ b1,
                                              __half* __restrict__ hsrc2,
                                              __half* __restrict__ hdst2) {
    __shared__ int cnt_lds[64];
    __shared__ int ell[64 * 64];
    __shared__ _Float16 agg[64][72];
    __shared__ _Float16 zt[4][16][136];
    int bkt = blockIdx.x;
    int ebase = base[bkt];
    int ecnt = hist[bkt];
    if (threadIdx.x < 64) cnt_lds[threadIdx.x] = 0;
    __syncthreads();
    for (int i = threadIdx.x; i < ecnt; i += 256) {
        int v = edgebuf[ebase + i];
        int ld = v & 63;
        int p = atomicAdd(&cnt_lds[ld], 1);
        if (p < 64) ell[(ld << 6) + p] = v >> 6;
    }
    __syncthreads();
    int wid = threadIdx.x >> 6, lane = threadIdx.x & 63;
    int sub = lane >> 3, fq = lane & 7;
    const H8* Xr = reinterpret_cast<const H8*>(X);
    for (int ld = wid; ld < 64; ld += 4) {
        int d = (bkt << 6) + ld;
        if (d >= N1) continue;               // wave-uniform
        int cn = cnt_lds[ld];
        int mm = cn < 64 ? cn : 64;
        float acc[8];
        #pragma unroll
        for (int i = 0; i < 8; ++i) acc[i] = 0.0f;
        for (int e = sub; e < mm; e += 8) {
            int sidx = ell[(ld << 6) + e];
            H8 p = Xr[(size_t)sidx * 8 + fq];
            float2 f0 = __half22float2(p.a);
            float2 f1 = __half22float2(p.b);
            float2 f2 = __half22float2(p.c);
            float2 f3 = __half22float2(p.d);
            acc[0] += f0.x; acc[1] += f0.y; acc[2] += f1.x; acc[3] += f1.y;
            acc[4] += f2.x; acc[5] += f2.y; acc[6] += f3.x; acc[7] += f3.y;
        }
        #pragma unroll
        for (int o = 8; o <= 32; o <<= 1) {
            #pragma unroll
            for (int i = 0; i < 8; ++i) acc[i] += __shfl_xor(acc[i], o, 64);
        }
        if (sub == 0) {
            float inv = (cn > 0) ? (1.0f / (float)cn) : 0.0f;
            H8 o;
            o.a = __floats2half2_rn(acc[0] * inv, acc[1] * inv);
            o.b = __floats2half2_rn(acc[2] * inv, acc[3] * inv);
            o.c = __floats2half2_rn(acc[4] * inv, acc[5] * inv);
            o.d = __floats2half2_rn(acc[6] * inv, acc[7] * inv);
            *reinterpret_cast<H8*>(&agg[ld][fq * 8]) = o;
        }
    }
    __syncthreads();
    // ---- Phase B ----
    int tile = bkt * 4 + wid;
    if (tile >= NT1) return;
    int r0 = tile * 16;
    int m = lane & 15, q = lane >> 4;
    int lm = wid * 16 + m;
    const _Float16* Ad = (const _Float16*)hdst1 + (size_t)(r0 + m) * 64 + q * 8;
    const _Float16* wt = (const _Float16*)wth;
    const _Float16* Wout  = wt + 16384;      // [128][64]
    const _Float16* Wsrc2 = wt + 24576;      // [64][128]
    const _Float16* Wdst2 = wt + 32768;      // [64][128]

    f32x4 acc2[8];
    #pragma unroll
    for (int nt = 0; nt < 8; ++nt) acc2[nt] = (f32x4)(0.0f);
    #pragma unroll
    for (int kc = 0; kc < 2; ++kc) {
        f16x8 az = *(const f16x8*)(&agg[lm][kc * 32 + q * 8]);
        f16x8 ad = *(const f16x8*)(Ad + kc * 32);
        f16x8 z;
        #pragma unroll
        for (int i = 0; i < 8; ++i) z[i] = (_Float16)((float)az[i] * (float)ad[i]);
        #pragma unroll
        for (int nt = 0; nt < 8; ++nt) {
            f16x8 bo = *(const f16x8*)(Wout + (nt * 16 + m) * 64 + kc * 32 + q * 8);
            acc2[nt] = MFMA16(z, bo, acc2[nt]);
        }
    }
    #pragma unroll
    for (int nt = 0; nt < 8; ++nt) {
        float bz = b1[nt * 16 + m];
        #pragma unroll
        for (int i = 0; i < 4; ++i) {
            float v = fmaxf(acc2[nt][i] + bz, 0.0f);
            zt[wid][q * 4 + i][nt * 16 + m] = (_Float16)v;
        }
    }
    // per-wave LDS ordering covers zt write->read (same wave's rows)
    f32x4 accS[4], accD[4];
    #pragma unroll
    for (int nt = 0; nt < 4; ++nt) { accS[nt] = (f32x4)(0.0f); accD[nt] = (f32x4)(0.0f); }
    bool do_dst = (tile < NT2);
    #pragma unroll
    for (int kc = 0; kc < 4; ++kc) {
        f16x8 ah = *(const f16x8*)(&zt[wid][m][kc * 32 + q * 8]);
        #pragma unroll
        for (int nt = 0; nt < 4; ++nt) {
            f16x8 bs = *(const f16x8*)(Wsrc2 + (nt * 16 + m) * 128 + kc * 32 + q * 8);
            accS[nt] = MFMA16(ah, bs, accS[nt]);
        }
        if (do_dst) {
            #pragma unroll
            for (int nt = 0; nt < 4; ++nt) {
                f16x8 bd = *(const f16x8*)(Wdst2 + (nt * 16 + m) * 128 + kc * 32 + q * 8);
                accD[nt] = MFMA16(ah, bd, accD[nt]);
            }
        }
    }
    #pragma unroll
    for (int nt = 0; nt < 4; ++nt)
        #pragma unroll
        for (int i = 0; i < 4; ++i)
            hsrc2[(size_t)(r0 + q * 4 + i) * 64 + nt * 16 + m] = __float2half(accS[nt][i]);
    if (do_dst) {
        #pragma unroll
        for (int nt = 0; nt < 4; ++nt)
            #pragma unroll
            for (int i = 0; i < 4; ++i)
                hdst2[(size_t)(r0 + q * 4 + i) * 64 + nt * 16 + m] = __float2half(accD[nt][i]);
    }
}

// ---------------------------------------------------------------------------
// K6: fused seg-mean(rank64) + layer2 -> out (f32). agg in LDS only.
__global__ __launch_bounds__(256) void seg2l2(const __half* __restrict__ X,
                                              const __half* __restrict__ hdst2,
                                              const int* __restrict__ edgebuf,
                                              const int* __restrict__ base,
                                              const int* __restrict__ hist,
                                              const __half* __restrict__ wth,
                                              const float* __restrict__ b2,
                                              float* __restrict__ out) {
    __shared__ int cnt_lds[64];
    __shared__ int ell[64 * 64];
    __shared__ _Float16 agg[64][72];
    int bkt = blockIdx.x;
    int gb = NB1 + bkt;
    int ebase = base[gb];
    int ecnt = hist[gb];
    if (threadIdx.x < 64) cnt_lds[threadIdx.x] = 0;
    __syncthreads();
    for (int i = threadIdx.x; i < ecnt; i += 256) {
        int v = edgebuf[ebase + i];
        int ld = v & 63;
        int p = atomicAdd(&cnt_lds[ld], 1);
        if (p < 64) ell[(ld << 6) + p] = v >> 6;
    }
    __syncthreads();
    int wid = threadIdx.x >> 6, lane = threadIdx.x & 63;
    int sub = lane >> 3, fq = lane & 7;
    const H8* Xr = reinterpret_cast<const H8*>(X);
    for (int ld = wid; ld < 64; ld += 4) {
        int d = (bkt << 6) + ld;
        if (d >= N2) continue;               // wave-uniform
        int cn = cnt_lds[ld];
        int mm = cn < 64 ? cn : 64;
        float acc[8];
        #pragma unroll
        for (int i = 0; i < 8; ++i) acc[i] = 0.0f;
        for (int e = sub; e < mm; e += 8) {
            int sidx = ell[(ld << 6) + e];
            H8 p = Xr[(size_t)sidx * 8 + fq];
            float2 f0 = __half22float2(p.a);
            float2 f1 = __half22float2(p.b);
            float2 f2 = __half22float2(p.c);
            float2 f3 = __half22float2(p.d);
            acc[0] += f0.x; acc[1] += f0.y; acc[2] += f1.x; acc[3] += f1.y;
            acc[4] += f2.x; acc[5] += f2.y; acc[6] += f3.x; acc[7] += f3.y;
        }
        #pragma unroll
        for (int o = 8; o <= 32; o <<= 1) {
            #pragma unroll
            for (int i = 0; i < 8; ++i) acc[i] += __shfl_xor(acc[i], o, 64);
        }
        if (sub == 0) {
            float inv = (cn > 0) ? (1.0f / (float)cn) : 0.0f;
            H8 o;
            o.a = __floats2half2_rn(acc[0] * inv, acc[1] * inv);
            o.b = __floats2half2_rn(acc[2] * inv, acc[3] * inv);
            o.c = __floats2half2_rn(acc[4] * inv, acc[5] * inv);
            o.d = __floats2half2_rn(acc[6] * inv, acc[7] * inv);
            *reinterpret_cast<H8*>(&agg[ld][fq * 8]) = o;
        }
    }
    __syncthreads();
    // ---- Phase B: out = (agg * hdst2) @ Wout2 + b2 ----
    int tile = bkt * 4 + wid;
    if (tile >= NT2) return;
    int r0 = tile * 16;
    int m = lane & 15, q = lane >> 4;
    int lm = wid * 16 + m;
    const _Float16* Ad = (const _Float16*)hdst2 + (size_t)(r0 + m) * 64 + q * 8;
    const _Float16* Wout = (const _Float16*)wth + 40960;   // [64][64]

    f32x4 acc[4];
    #pragma unroll
    for (int nt = 0; nt < 4; ++nt) acc[nt] = (f32x4)(0.0f);
    #pragma unroll
    for (int kc = 0; kc < 2; ++kc) {
        f16x8 az = *(const f16x8*)(&agg[lm][kc * 32 + q * 8]);
        f16x8 ad = *(const f16x8*)(Ad + kc * 32);
        f16x8 z;
        #pragma unroll
        for (int i = 0; i < 8; ++i) z[i] = (_Float16)((float)az[i] * (float)ad[i]);
        #pragma unroll
        for (int nt = 0; nt < 4; ++nt) {
            f16x8 bo = *(const f16x8*)(Wout + (nt * 16 + m) * 64 + kc * 32 + q * 8);
            acc[nt] = MFMA16(z, bo, acc[nt]);
        }
    }
    #pragma unroll
    for (int nt = 0; nt < 4; ++nt) {
        float bz = b2[nt * 16 + m];
        #pragma unroll
        for (int i = 0; i < 4; ++i)
            out[(size_t)(r0 + q * 4 + i) * 64 + nt * 16 + m] = acc[nt][i] + bz;
    }
}

// ---------------------------------------------------------------------------
extern "C" void kernel_launch(void* const* d_in, const int* in_sizes, int n_in,
                              void* d_out, int out_size, void* d_ws, size_t ws_size,
                              hipStream_t stream) {
    const float* x     = (const float*)d_in[0];
    const float* Wsrc1 = (const float*)d_in[1];
    const float* Wdst1 = (const float*)d_in[2];
    const float* Wout1 = (const float*)d_in[3];
    const float* b1    = (const float*)d_in[4];
    const float* Wsrc2 = (const float*)d_in[5];
    const float* Wdst2 = (const float*)d_in[6];
    const float* Wout2 = (const float*)d_in[7];
    const float* b2    = (const float*)d_in[8];
    const int* src1    = (const int*)d_in[9];
    const int* dst1    = (const int*)d_in[10];
    const int* src2    = (const int*)d_in[11];
    const int* dst2    = (const int*)d_in[12];
    float* out = (float*)d_out;

    // workspace layout (byte offsets, 16B-aligned)
    char* basep = (char*)d_ws;
    __half* hsrc1 = (__half*)(basep);                  // 25.6 MB  [N0][64]
    __half* hdst1 = (__half*)(basep + 25600000);       //  6.4 MB  [N1][64]
    __half* hsrc2 = (__half*)(basep + 32000000);       //  6.4 MB  [N1][64]
    __half* hdst2 = (__half*)(basep + 38400000);       // 1.28 MB  [N2][64]
    int* hist     = (int*)(basep + 39680000);          // NBT
    int* bbase    = (int*)(basep + 39683776);          // NBT
    int* cursor   = (int*)(basep + 39687552);          // NBT
    int* histp    = (int*)(basep + 39691328);          // 64*784 + 16*160
    int* edgebuf  = (int*)(basep + 39902272);          // 960000 ints
    __half* wt    = (__half*)(basep + 43742272);       // 90 KB transposed weights

    prep_count<<<CH1 + CH2 + WT_TOTAL / 256, 256, 0, stream>>>(dst1, dst2, histp,
                                                               Wsrc1, Wdst1, Wout1, Wsrc2, Wdst2, Wout2, wt);
    scan_sum<<<1, 1024, 0, stream>>>(histp, hist, bbase, cursor);
    sort_scatter<<<8 * CH1 + 8 * CH2, 256, 0, stream>>>(dst1, src1, dst2, src2, cursor, edgebuf);
    proj1<<<(NTP + 3) / 4, 256, 0, stream>>>(x, wt, hsrc1, hdst1);
    seg1l1<<<782, 256, 0, stream>>>(hsrc1, hdst1, edgebuf, bbase, hist, wt, b1, hsrc2, hdst2);
    seg2l2<<<157, 256, 0, stream>>>(hsrc2, hdst2, edgebuf, bbase, hist, wt, b2, out);
}

// Round 4
// 276.053 us; speedup vs baseline: 1.1552x; 1.1552x over previous
//
#include <hip/hip_runtime.h>
#include <hip/hip_bf16.h>
#include <hip/hip_fp16.h>

// Problem constants
#define N0 200000
#define N1 50000
#define N2 10000
#define E1C 800000
#define E2C 160000
// IN_F=128, HID=128, RANK=64, OUT_C=64
#define NB1 784      // ceil(50000/64)=782, padded to mult of 8
#define NB2 160      // ceil(10000/64)=157, padded to mult of 8
#define NBT (NB1 + NB2)
#define CH1 64
#define CH2 16
#define NTP 12500    // N0/16 projection tiles
#define NT1 3125     // N1/16
#define NT2 625      // N2/16
#define SCAP 2048    // LDS sort capacity (expected 1562, +13 sigma)

struct H8 { __half2 a, b, c, d; };        // 16 B

typedef _Float16 f16x8 __attribute__((ext_vector_type(8)));
typedef float f32x4 __attribute__((ext_vector_type(4)));
#define MFMA16(a, b, c) __builtin_amdgcn_mfma_f32_16x16x32_f16(a, b, c, 0, 0, 0)

// Transposed fp16 weight block offsets (halves):
// Wsrc1t[64][128]@0, Wdst1t[64][128]@8192, Wout1t[128][64]@16384,
// Wsrc2t[64][128]@24576, Wdst2t[64][128]@32768, Wout2t[64][64]@40960
#define WT_TOTAL 45056

// ---------------------------------------------------------------------------
// K1: blocks 0..79 = per-chunk histograms into PRIVATE slices (no zero, no
// global atomics); remaining blocks = fp16 transposed weight build.
__global__ __launch_bounds__(256) void prep_count(const int* __restrict__ dst1,
                                                  const int* __restrict__ dst2,
                                                  int* __restrict__ hist_part,
                                                  const float* __restrict__ Wsrc1,
                                                  const float* __restrict__ Wdst1,
                                                  const float* __restrict__ Wout1,
                                                  const float* __restrict__ Wsrc2,
                                                  const float* __restrict__ Wdst2,
                                                  const float* __restrict__ Wout2,
                                                  __half* __restrict__ wt) {
    int b = blockIdx.x;
    if (b < CH1 + CH2) {
        __shared__ int hl[NB1];
        const int* dst; int nb, e0, n4, hoff;
        if (b < CH1) {
            dst = dst1; nb = NB1; int per = E1C / CH1 / 4; e0 = b * per; n4 = per;
            hoff = b * NB1;
        } else {
            dst = dst2; nb = NB2; int per = E2C / CH2 / 4; int c = b - CH1;
            e0 = c * per; n4 = per;
            hoff = CH1 * NB1 + c * NB2;
        }
        for (int i = threadIdx.x; i < nb; i += 256) hl[i] = 0;
        __syncthreads();
        const int4* d4 = reinterpret_cast<const int4*>(dst);
        for (int i = e0 + threadIdx.x; i < e0 + n4; i += 256) {
            int4 v = d4[i];
            atomicAdd(&hl[v.x >> 6], 1);
            atomicAdd(&hl[v.y >> 6], 1);
            atomicAdd(&hl[v.z >> 6], 1);
            atomicAdd(&hl[v.w >> 6], 1);
        }
        __syncthreads();
        for (int i = threadIdx.x; i < nb; i += 256) hist_part[hoff + i] = hl[i];
    } else {
        int e = (b - (CH1 + CH2)) * 256 + threadIdx.x;
        if (e < WT_TOTAL) {
            float v;
            if (e < 8192)       { int e2 = e;         int n = e2 >> 7, k = e2 & 127; v = Wsrc1[k * 64 + n]; }
            else if (e < 16384) { int e2 = e - 8192;  int n = e2 >> 7, k = e2 & 127; v = Wdst1[k * 64 + n]; }
            else if (e < 24576) { int e2 = e - 16384; int n = e2 >> 6, k = e2 & 63;  v = Wout1[k * 128 + n]; }
            else if (e < 32768) { int e2 = e - 24576; int n = e2 >> 7, k = e2 & 127; v = Wsrc2[k * 64 + n]; }
            else if (e < 40960) { int e2 = e - 32768; int n = e2 >> 7, k = e2 & 127; v = Wdst2[k * 64 + n]; }
            else                { int e2 = e - 40960; int n = e2 >> 6, k = e2 & 63;  v = Wout2[k * 64 + n]; }
            wt[e] = __float2half(v);
        }
    }
}

// ---------------------------------------------------------------------------
// K2: sum private slices -> hist, exclusive scan -> base, cursor.
__global__ __launch_bounds__(1024) void scan_sum(const int* __restrict__ hp,
                                                 int* __restrict__ hist,
                                                 int* __restrict__ base,
                                                 int* __restrict__ cursor) {
    int t = threadIdx.x, lane = t & 63, wid = t >> 6;
    int v = 0;
    if (t < NB1) {
        #pragma unroll 8
        for (int c = 0; c < CH1; ++c) v += hp[c * NB1 + t];
    } else if (t < NBT) {
        const int* hp2 = hp + CH1 * NB1;
        int j = t - NB1;
        #pragma unroll
        for (int c = 0; c < CH2; ++c) v += hp2[c * NB2 + j];
    }
    if (t < NBT) hist[t] = v;
    int s = v;
    #pragma unroll
    for (int o = 1; o < 64; o <<= 1) { int u = __shfl_up(s, o, 64); if (lane >= o) s += u; }
    __shared__ int ws[16];
    if (lane == 63) ws[wid] = s;
    __syncthreads();
    if (wid == 0 && lane < 16) {
        int w = ws[lane];
        #pragma unroll
        for (int o = 1; o < 16; o <<= 1) { int u = __shfl_up(w, o, 64); if (lane >= o) w += u; }
        ws[lane] = w;
    }
    __syncthreads();
    int excl = ((wid == 0) ? 0 : ws[wid - 1]) + (s - v);
    if (t < NBT) { base[t] = excl; cursor[t] = excl; }
}

// ---------------------------------------------------------------------------
// K3: LDS counting-sort scatter (unchanged).
__global__ __launch_bounds__(256) void sort_scatter(const int* __restrict__ dst1,
                                                    const int* __restrict__ src1,
                                                    const int* __restrict__ dst2,
                                                    const int* __restrict__ src2,
                                                    int* __restrict__ cursor,
                                                    int* __restrict__ edgebuf) {
    __shared__ int cnt_l[98], lbase[98], rsv[98], lcur[98];
    __shared__ int slot[SCAP];
    __shared__ int stot[2];
    int b = blockIdx.x;
    const int* dst; const int* srcp; int goff, bpp, lo, e0, e1;
    if (b < 8 * CH1) {
        dst = dst1; srcp = src1; goff = 0; bpp = NB1 / 8;
        int part = b & 7, chunk = b >> 3;
        lo = part * bpp;
        int per = E1C / CH1 / 4;
        e0 = chunk * per; e1 = e0 + per;
    } else {
        int k = b - 8 * CH1;
        dst = dst2; srcp = src2; goff = NB1; bpp = NB2 / 8;
        int part = k & 7, chunk = k >> 3;
        lo = part * bpp;
        int per = E2C / CH2 / 4;
        e0 = chunk * per; e1 = e0 + per;
    }
    int t = threadIdx.x;
    for (int i = t; i < bpp; i += 256) { cnt_l[i] = 0; lcur[i] = 0; }
    __syncthreads();
    const int4* d4 = reinterpret_cast<const int4*>(dst);
    const int4* s4 = reinterpret_cast<const int4*>(srcp);
    for (int i = e0 + t; i < e1; i += 256) {
        int4 v = d4[i];
        int b0 = (v.x >> 6) - lo; if ((unsigned)b0 < (unsigned)bpp) atomicAdd(&cnt_l[b0], 1);
        int b1 = (v.y >> 6) - lo; if ((unsigned)b1 < (unsigned)bpp) atomicAdd(&cnt_l[b1], 1);
        int b2 = (v.z >> 6) - lo; if ((unsigned)b2 < (unsigned)bpp) atomicAdd(&cnt_l[b2], 1);
        int b3 = (v.w >> 6) - lo; if ((unsigned)b3 < (unsigned)bpp) atomicAdd(&cnt_l[b3], 1);
    }
    __syncthreads();
    if (t < 128) {
        int j = t;
        int lane6 = t & 63;
        int v = (j < bpp) ? cnt_l[j] : 0;
        int s = v;
        #pragma unroll
        for (int o = 1; o < 64; o <<= 1) { int u = __shfl_up(s, o, 64); if (lane6 >= o) s += u; }
        if (lane6 == 63) stot[t >> 6] = s;
        if (j < bpp) lbase[j] = s - v;
    }
    __syncthreads();
    if (t >= 64 && t < 128) {
        int j = t;
        if (j < bpp) lbase[j] += stot[0];
    }
    __syncthreads();
    int T = stot[0] + stot[1];
    if (T <= SCAP) {
        for (int i = e0 + t; i < e1; i += 256) {
            int4 dv = d4[i];
            int4 sv = s4[i];
            int b0 = (dv.x >> 6) - lo;
            if ((unsigned)b0 < (unsigned)bpp) { int p = atomicAdd(&lcur[b0], 1); slot[lbase[b0] + p] = (b0 << 24) | (sv.x << 6) | (dv.x & 63); }
            int b1 = (dv.y >> 6) - lo;
            if ((unsigned)b1 < (unsigned)bpp) { int p = atomicAdd(&lcur[b1], 1); slot[lbase[b1] + p] = (b1 << 24) | (sv.y << 6) | (dv.y & 63); }
            int b2 = (dv.z >> 6) - lo;
            if ((unsigned)b2 < (unsigned)bpp) { int p = atomicAdd(&lcur[b2], 1); slot[lbase[b2] + p] = (b2 << 24) | (sv.z << 6) | (dv.z & 63); }
            int b3 = (dv.w >> 6) - lo;
            if ((unsigned)b3 < (unsigned)bpp) { int p = atomicAdd(&lcur[b3], 1); slot[lbase[b3] + p] = (b3 << 24) | (sv.w << 6) | (dv.w & 63); }
        }
        if (t < bpp) rsv[t] = cnt_l[t] ? atomicAdd(&cursor[goff + lo + t], cnt_l[t]) : 0;
        __syncthreads();
        for (int u = t; u < T; u += 256) {
            int w = slot[u];
            int bx = (unsigned)w >> 24;
            edgebuf[rsv[bx] + (u - lbase[bx])] = w & 0x00FFFFFF;
        }
    } else {
        if (t < bpp) rsv[t] = cnt_l[t] ? atomicAdd(&cursor[goff + lo + t], cnt_l[t]) : 0;
        __syncthreads();
        for (int i = e0 + t; i < e1; i += 256) {
            int4 dv = d4[i];
            int4 sv = s4[i];
            int b0 = (dv.x >> 6) - lo;
            if ((unsigned)b0 < (unsigned)bpp) { int p = atomicAdd(&lcur[b0], 1); edgebuf[rsv[b0] + p] = (sv.x << 6) | (dv.x & 63); }
            int b1 = (dv.y >> 6) - lo;
            if ((unsigned)b1 < (unsigned)bpp) { int p = atomicAdd(&lcur[b1], 1); edgebuf[rsv[b1] + p] = (sv.y << 6) | (dv.y & 63); }
            int b2 = (dv.z >> 6) - lo;
            if ((unsigned)b2 < (unsigned)bpp) { int p = atomicAdd(&lcur[b2], 1); edgebuf[rsv[b2] + p] = (sv.z << 6) | (dv.z & 63); }
            int b3 = (dv.w >> 6) - lo;
            if ((unsigned)b3 < (unsigned)bpp) { int p = atomicAdd(&lcur[b3], 1); edgebuf[rsv[b3] + p] = (sv.w << 6) | (dv.w & 63); }
        }
    }
}

// ---------------------------------------------------------------------------
// K4: proj1 (unchanged): h_src1 = fp16(x @ Wsrc1) all rows; h_dst1 for rows<N1.
__global__ __launch_bounds__(256) void proj1(const float* __restrict__ x,
                                             const __half* __restrict__ wth,
                                             __half* __restrict__ hsrc,
                                             __half* __restrict__ hdst) {
    int wave = threadIdx.x >> 6, lane = threadIdx.x & 63;
    int tile = blockIdx.x * 4 + wave;
    if (tile >= NTP) return;
    int r0 = tile * 16;
    int m = lane & 15, q = lane >> 4;
    const float* A = x + (size_t)(r0 + m) * 128 + q * 8;
    const _Float16* wt = (const _Float16*)wth;
    const _Float16* Wsrc = wt;               // [64][128]
    const _Float16* Wdst = wt + 8192;        // [64][128]

    f16x8 a[4];
    #pragma unroll
    for (int kc = 0; kc < 4; ++kc) {
        float4 v0 = *(const float4*)(A + kc * 32);
        float4 v1 = *(const float4*)(A + kc * 32 + 4);
        f16x8 tv;
        tv[0] = (_Float16)v0.x; tv[1] = (_Float16)v0.y; tv[2] = (_Float16)v0.z; tv[3] = (_Float16)v0.w;
        tv[4] = (_Float16)v1.x; tv[5] = (_Float16)v1.y; tv[6] = (_Float16)v1.z; tv[7] = (_Float16)v1.w;
        a[kc] = tv;
    }
    f32x4 accS[4];
    #pragma unroll
    for (int nt = 0; nt < 4; ++nt) accS[nt] = (f32x4)(0.0f);
    #pragma unroll
    for (int kc = 0; kc < 4; ++kc)
        #pragma unroll
        for (int nt = 0; nt < 4; ++nt) {
            f16x8 bb = *(const f16x8*)(Wsrc + (nt * 16 + m) * 128 + kc * 32 + q * 8);
            accS[nt] = MFMA16(a[kc], bb, accS[nt]);
        }
    #pragma unroll
    for (int nt = 0; nt < 4; ++nt)
        #pragma unroll
        for (int i = 0; i < 4; ++i)
            hsrc[(size_t)(r0 + q * 4 + i) * 64 + nt * 16 + m] = __float2half(accS[nt][i]);

    if (tile < NT1) {
        f32x4 accD[4];
        #pragma unroll
        for (int nt = 0; nt < 4; ++nt) accD[nt] = (f32x4)(0.0f);
        #pragma unroll
        for (int kc = 0; kc < 4; ++kc)
            #pragma unroll
            for (int nt = 0; nt < 4; ++nt) {
                f16x8 bb = *(const f16x8*)(Wdst + (nt * 16 + m) * 128 + kc * 32 + q * 8);
                accD[nt] = MFMA16(a[kc], bb, accD[nt]);
            }
        #pragma unroll
        for (int nt = 0; nt < 4; ++nt)
            #pragma unroll
            for (int i = 0; i < 4; ++i)
                hdst[(size_t)(r0 + q * 4 + i) * 64 + nt * 16 + m] = __float2half(accD[nt][i]);
    }
}

// ---------------------------------------------------------------------------
// K5: fused seg-mean(rank64) + layer1, 4-way bucket split for occupancy.
// Block = 16 dsts = exactly one 16-row MFMA tile. 4 waves gather (4 dsts
// each, 2-deep load ILP); wave 0 runs the fused MFMA tail.
__global__ __launch_bounds__(256) void seg1l1(const __half* __restrict__ X,
                                              const __half* __restrict__ hdst1,
                                              const int* __restrict__ edgebuf,
                                              const int* __restrict__ base,
                                              const int* __restrict__ hist,
                                              const __half* __restrict__ wth,
                                              const float* __restrict__ b1,
                                              __half* __restrict__ hsrc2,
                                              __half* __restrict__ hdst2) {
    __shared__ int cnt_lds[16];
    __shared__ int ell[16 * 64];
    __shared__ _Float16 agg[16][72];
    __shared__ _Float16 zt[16][136];
    int bkt = blockIdx.x >> 2, s = blockIdx.x & 3;
    int d0 = (bkt << 6) + (s << 4);
    if (d0 >= N1) return;                    // block-uniform
    int ebase = base[bkt];
    int ecnt = hist[bkt];
    if (threadIdx.x < 16) cnt_lds[threadIdx.x] = 0;
    __syncthreads();
    int lo16 = s << 4;
    for (int i = threadIdx.x; i < ecnt; i += 256) {
        int v = edgebuf[ebase + i];
        int ld = (v & 63) - lo16;
        if ((unsigned)ld < 16u) {
            int p = atomicAdd(&cnt_lds[ld], 1);
            if (p < 64) ell[(ld << 6) + p] = v >> 6;
        }
    }
    __syncthreads();
    int wid = threadIdx.x >> 6, lane = threadIdx.x & 63;
    int sub = lane >> 3, fq = lane & 7;
    const H8* Xr = reinterpret_cast<const H8*>(X);
    #pragma unroll
    for (int j = 0; j < 4; ++j) {
        int ld = wid * 4 + j;
        int cn = cnt_lds[ld];
        int mm = cn < 64 ? cn : 64;
        float acc[8];
        #pragma unroll
        for (int i = 0; i < 8; ++i) acc[i] = 0.0f;
        int e = sub;
        for (; e + 8 < mm; e += 16) {        // 2 loads in flight
            int s0 = ell[(ld << 6) + e];
            int s1 = ell[(ld << 6) + e + 8];
            H8 p0 = Xr[(size_t)s0 * 8 + fq];
            H8 p1 = Xr[(size_t)s1 * 8 + fq];
            float2 f0 = __half22float2(p0.a), g0 = __half22float2(p1.a);
            float2 f1 = __half22float2(p0.b), g1 = __half22float2(p1.b);
            float2 f2 = __half22float2(p0.c), g2 = __half22float2(p1.c);
            float2 f3 = __half22float2(p0.d), g3 = __half22float2(p1.d);
            acc[0] += f0.x + g0.x; acc[1] += f0.y + g0.y;
            acc[2] += f1.x + g1.x; acc[3] += f1.y + g1.y;
            acc[4] += f2.x + g2.x; acc[5] += f2.y + g2.y;
            acc[6] += f3.x + g3.x; acc[7] += f3.y + g3.y;
        }
        if (e < mm) {
            int s0 = ell[(ld << 6) + e];
            H8 p0 = Xr[(size_t)s0 * 8 + fq];
            float2 f0 = __half22float2(p0.a);
            float2 f1 = __half22float2(p0.b);
            float2 f2 = __half22float2(p0.c);
            float2 f3 = __half22float2(p0.d);
            acc[0] += f0.x; acc[1] += f0.y; acc[2] += f1.x; acc[3] += f1.y;
            acc[4] += f2.x; acc[5] += f2.y; acc[6] += f3.x; acc[7] += f3.y;
        }
        #pragma unroll
        for (int o = 8; o <= 32; o <<= 1) {
            #pragma unroll
            for (int i = 0; i < 8; ++i) acc[i] += __shfl_xor(acc[i], o, 64);
        }
        if (sub == 0) {
            float inv = (cn > 0) ? (1.0f / (float)cn) : 0.0f;
            H8 o;
            o.a = __floats2half2_rn(acc[0] * inv, acc[1] * inv);
            o.b = __floats2half2_rn(acc[2] * inv, acc[3] * inv);
            o.c = __floats2half2_rn(acc[4] * inv, acc[5] * inv);
            o.d = __floats2half2_rn(acc[6] * inv, acc[7] * inv);
            *reinterpret_cast<H8*>(&agg[ld][fq * 8]) = o;
        }
    }
    __syncthreads();
    // ---- Phase B: wave 0 only, one 16-row tile ----
    if (wid != 0) return;
    int tile = (bkt << 2) + s;               // = d0/16, < NT1 guaranteed
    int r0 = d0;
    int m = lane & 15, q = lane >> 4;
    const _Float16* Ad = (const _Float16*)hdst1 + (size_t)(r0 + m) * 64 + q * 8;
    const _Float16* wt = (const _Float16*)wth;
    const _Float16* Wout  = wt + 16384;      // [128][64]
    const _Float16* Wsrc2 = wt + 24576;      // [64][128]
    const _Float16* Wdst2 = wt + 32768;      // [64][128]

    f32x4 acc2[8];
    #pragma unroll
    for (int nt = 0; nt < 8; ++nt) acc2[nt] = (f32x4)(0.0f);
    #pragma unroll
    for (int kc = 0; kc < 2; ++kc) {
        f16x8 az = *(const f16x8*)(&agg[m][kc * 32 + q * 8]);
        f16x8 ad = *(const f16x8*)(Ad + kc * 32);
        f16x8 z;
        #pragma unroll
        for (int i = 0; i < 8; ++i) z[i] = (_Float16)((float)az[i] * (float)ad[i]);
        #pragma unroll
        for (int nt = 0; nt < 8; ++nt) {
            f16x8 bo = *(const f16x8*)(Wout + (nt * 16 + m) * 64 + kc * 32 + q * 8);
            acc2[nt] = MFMA16(z, bo, acc2[nt]);
        }
    }
    #pragma unroll
    for (int nt = 0; nt < 8; ++nt) {
        float bz = b1[nt * 16 + m];
        #pragma unroll
        for (int i = 0; i < 4; ++i) {
            float v = fmaxf(acc2[nt][i] + bz, 0.0f);
            zt[q * 4 + i][nt * 16 + m] = (_Float16)v;
        }
    }
    // per-wave LDS ordering covers zt write->read (only wave 0 touches zt)
    f32x4 accS[4], accD[4];
    #pragma unroll
    for (int nt = 0; nt < 4; ++nt) { accS[nt] = (f32x4)(0.0f); accD[nt] = (f32x4)(0.0f); }
    bool do_dst = (tile < NT2);
    #pragma unroll
    for (int kc = 0; kc < 4; ++kc) {
        f16x8 ah = *(const f16x8*)(&zt[m][kc * 32 + q * 8]);
        #pragma unroll
        for (int nt = 0; nt < 4; ++nt) {
            f16x8 bs = *(const f16x8*)(Wsrc2 + (nt * 16 + m) * 128 + kc * 32 + q * 8);
            accS[nt] = MFMA16(ah, bs, accS[nt]);
        }
        if (do_dst) {
            #pragma unroll
            for (int nt = 0; nt < 4; ++nt) {
                f16x8 bd = *(const f16x8*)(Wdst2 + (nt * 16 + m) * 128 + kc * 32 + q * 8);
                accD[nt] = MFMA16(ah, bd, accD[nt]);
            }
        }
    }
    #pragma unroll
    for (int nt = 0; nt < 4; ++nt)
        #pragma unroll
        for (int i = 0; i < 4; ++i)
            hsrc2[(size_t)(r0 + q * 4 + i) * 64 + nt * 16 + m] = __float2half(accS[nt][i]);
    if (do_dst) {
        #pragma unroll
        for (int nt = 0; nt < 4; ++nt)
            #pragma unroll
            for (int i = 0; i < 4; ++i)
                hdst2[(size_t)(r0 + q * 4 + i) * 64 + nt * 16 + m] = __float2half(accD[nt][i]);
    }
}

// ---------------------------------------------------------------------------
// K6: fused seg-mean(rank64) + layer2 -> out (f32), 4-way bucket split.
__global__ __launch_bounds__(256) void seg2l2(const __half* __restrict__ X,
                                              const __half* __restrict__ hdst2,
                                              const int* __restrict__ edgebuf,
                                              const int* __restrict__ base,
                                              const int* __restrict__ hist,
                                              const __half* __restrict__ wth,
                                              const float* __restrict__ b2,
                                              float* __restrict__ out) {
    __shared__ int cnt_lds[16];
    __shared__ int ell[16 * 64];
    __shared__ _Float16 agg[16][72];
    int bkt = blockIdx.x >> 2, s = blockIdx.x & 3;
    int d0 = (bkt << 6) + (s << 4);
    if (d0 >= N2) return;
    int gb = NB1 + bkt;
    int ebase = base[gb];
    int ecnt = hist[gb];
    if (threadIdx.x < 16) cnt_lds[threadIdx.x] = 0;
    __syncthreads();
    int lo16 = s << 4;
    for (int i = threadIdx.x; i < ecnt; i += 256) {
        int v = edgebuf[ebase + i];
        int ld = (v & 63) - lo16;
        if ((unsigned)ld < 16u) {
            int p = atomicAdd(&cnt_lds[ld], 1);
            if (p < 64) ell[(ld << 6) + p] = v >> 6;
        }
    }
    __syncthreads();
    int wid = threadIdx.x >> 6, lane = threadIdx.x & 63;
    int sub = lane >> 3, fq = lane & 7;
    const H8* Xr = reinterpret_cast<const H8*>(X);
    #pragma unroll
    for (int j = 0; j < 4; ++j) {
        int ld = wid * 4 + j;
        int cn = cnt_lds[ld];
        int mm = cn < 64 ? cn : 64;
        float acc[8];
        #pragma unroll
        for (int i = 0; i < 8; ++i) acc[i] = 0.0f;
        int e = sub;
        for (; e + 8 < mm; e += 16) {
            int s0 = ell[(ld << 6) + e];
            int s1 = ell[(ld << 6) + e + 8];
            H8 p0 = Xr[(size_t)s0 * 8 + fq];
            H8 p1 = Xr[(size_t)s1 * 8 + fq];
            float2 f0 = __half22float2(p0.a), g0 = __half22float2(p1.a);
            float2 f1 = __half22float2(p0.b), g1 = __half22float2(p1.b);
            float2 f2 = __half22float2(p0.c), g2 = __half22float2(p1.c);
            float2 f3 = __half22float2(p0.d), g3 = __half22float2(p1.d);
            acc[0] += f0.x + g0.x; acc[1] += f0.y + g0.y;
            acc[2] += f1.x + g1.x; acc[3] += f1.y + g1.y;
            acc[4] += f2.x + g2.x; acc[5] += f2.y + g2.y;
            acc[6] += f3.x + g3.x; acc[7] += f3.y + g3.y;
        }
        if (e < mm) {
            int s0 = ell[(ld << 6) + e];
            H8 p0 = Xr[(size_t)s0 * 8 + fq];
            float2 f0 = __half22float2(p0.a);
            float2 f1 = __half22float2(p0.b);
            float2 f2 = __half22float2(p0.c);
            float2 f3 = __half22float2(p0.d);
            acc[0] += f0.x; acc[1] += f0.y; acc[2] += f1.x; acc[3] += f1.y;
            acc[4] += f2.x; acc[5] += f2.y; acc[6] += f3.x; acc[7] += f3.y;
        }
        #pragma unroll
        for (int o = 8; o <= 32; o <<= 1) {
            #pragma unroll
            for (int i = 0; i < 8; ++i) acc[i] += __shfl_xor(acc[i], o, 64);
        }
        if (sub == 0) {
            float inv = (cn > 0) ? (1.0f / (float)cn) : 0.0f;
            H8 o;
            o.a = __floats2half2_rn(acc[0] * inv, acc[1] * inv);
            o.b = __floats2half2_rn(acc[2] * inv, acc[3] * inv);
            o.c = __floats2half2_rn(acc[4] * inv, acc[5] * inv);
            o.d = __floats2half2_rn(acc[6] * inv, acc[7] * inv);
            *reinterpret_cast<H8*>(&agg[ld][fq * 8]) = o;
        }
    }
    __syncthreads();
    // ---- Phase B: out = (agg * hdst2) @ Wout2 + b2, wave 0 only ----
    if (wid != 0) return;
    int r0 = d0;
    int m = lane & 15, q = lane >> 4;
    const _Float16* Ad = (const _Float16*)hdst2 + (size_t)(r0 + m) * 64 + q * 8;
    const _Float16* Wout = (const _Float16*)wth + 40960;   // [64][64]

    f32x4 acc[4];
    #pragma unroll
    for (int nt = 0; nt < 4; ++nt) acc[nt] = (f32x4)(0.0f);
    #pragma unroll
    for (int kc = 0; kc < 2; ++kc) {
        f16x8 az = *(const f16x8*)(&agg[m][kc * 32 + q * 8]);
        f16x8 ad = *(const f16x8*)(Ad + kc * 32);
        f16x8 z;
        #pragma unroll
        for (int i = 0; i < 8; ++i) z[i] = (_Float16)((float)az[i] * (float)ad[i]);
        #pragma unroll
        for (int nt = 0; nt < 4; ++nt) {
            f16x8 bo = *(const f16x8*)(Wout + (nt * 16 + m) * 64 + kc * 32 + q * 8);
            acc[nt] = MFMA16(z, bo, acc[nt]);
        }
    }
    #pragma unroll
    for (int nt = 0; nt < 4; ++nt) {
        float bz = b2[nt * 16 + m];
        #pragma unroll
        for (int i = 0; i < 4; ++i)
            out[(size_t)(r0 + q * 4 + i) * 64 + nt * 16 + m] = acc[nt][i] + bz;
    }
}

// ---------------------------------------------------------------------------
extern "C" void kernel_launch(void* const* d_in, const int* in_sizes, int n_in,
                              void* d_out, int out_size, void* d_ws, size_t ws_size,
                              hipStream_t stream) {
    const float* x     = (const float*)d_in[0];
    const float* Wsrc1 = (const float*)d_in[1];
    const float* Wdst1 = (const float*)d_in[2];
    const float* Wout1 = (const float*)d_in[3];
    const float* b1    = (const float*)d_in[4];
    const float* Wsrc2 = (const float*)d_in[5];
    const float* Wdst2 = (const float*)d_in[6];
    const float* Wout2 = (const float*)d_in[7];
    const float* b2    = (const float*)d_in[8];
    const int* src1    = (const int*)d_in[9];
    const int* dst1    = (const int*)d_in[10];
    const int* src2    = (const int*)d_in[11];
    const int* dst2    = (const int*)d_in[12];
    float* out = (float*)d_out;

    // workspace layout (byte offsets, 16B-aligned)
    char* basep = (char*)d_ws;
    __half* hsrc1 = (__half*)(basep);                  // 25.6 MB  [N0][64]
    __half* hdst1 = (__half*)(basep + 25600000);       //  6.4 MB  [N1][64]
    __half* hsrc2 = (__half*)(basep + 32000000);       //  6.4 MB  [N1][64]
    __half* hdst2 = (__half*)(basep + 38400000);       // 1.28 MB  [N2][64]
    int* hist     = (int*)(basep + 39680000);          // NBT
    int* bbase    = (int*)(basep + 39683776);          // NBT
    int* cursor   = (int*)(basep + 39687552);          // NBT
    int* histp    = (int*)(basep + 39691328);          // 64*784 + 16*160
    int* edgebuf  = (int*)(basep + 39902272);          // 960000 ints
    __half* wt    = (__half*)(basep + 43742272);       // 90 KB transposed weights

    prep_count<<<CH1 + CH2 + WT_TOTAL / 256, 256, 0, stream>>>(dst1, dst2, histp,
                                                               Wsrc1, Wdst1, Wout1, Wsrc2, Wdst2, Wout2, wt);
    scan_sum<<<1, 1024, 0, stream>>>(histp, hist, bbase, cursor);
    sort_scatter<<<8 * CH1 + 8 * CH2, 256, 0, stream>>>(dst1, src1, dst2, src2, cursor, edgebuf);
    proj1<<<(NTP + 3) / 4, 256, 0, stream>>>(x, wt, hsrc1, hdst1);
    seg1l1<<<782 * 4, 256, 0, stream>>>(hsrc1, hdst1, edgebuf, bbase, hist, wt, b1, hsrc2, hdst2);
    seg2l2<<<157 * 4, 256, 0, stream>>>(hsrc2, hdst2, edgebuf, bbase, hist, wt, b2, out);
}